// Round 3
// baseline (418.694 us; speedup 1.0000x reference)
//
#include <hip/hip_runtime.h>
#include <hip/hip_bf16.h>

// GoSpecificWattiPooling: K=H*Wk^T, Q=G*Wq^T, A=softmax(QK^T/16), Z=A*H
// Round 2 resubmit (rounds 0-1 were GPU-acquisition timeouts; no signal).
// bf16-MFMA pipeline: transpose_h, proj x2, attn-alpha (unnormalized E + row
// sums), pv with deferred normalization.

static constexpr int BB = 16;    // batch
static constexpr int LL = 2048;  // keys
static constexpr int TT = 512;   // queries
static constexpr int DH = 1024;  // H dim
static constexpr int DG = 768;   // G dim
static constexpr int PP = 256;   // proj dim

typedef short s16x8 __attribute__((ext_vector_type(8)));
typedef float f32x4 __attribute__((ext_vector_type(4)));

__device__ __forceinline__ unsigned short f2bf(float f) {
  __hip_bfloat16 h = __float2bfloat16(f);
  return __builtin_bit_cast(unsigned short, h);
}

// ---------------------------------------------------------------- transpose
// H (f32, [b][l][d]) -> Ht (bf16, [b][d][l]); 64x64 tiles via LDS.
__global__ __launch_bounds__(256) void k_transpose_h(
    const float* __restrict__ H, unsigned short* __restrict__ Ht) {
  __shared__ unsigned short tile[64][68];  // [d][l], stride 68 keeps 8B align
  const int l0 = blockIdx.x * 64;
  const int d0 = blockIdx.y * 64;
  const int b = blockIdx.z;
  const int t = threadIdx.x;
#pragma unroll
  for (int i = 0; i < 4; ++i) {
    int s = i * 256 + t;
    int l = s >> 4;          // 0..63
    int d = (s & 15) * 4;    // 0..60
    const float4 v = *reinterpret_cast<const float4*>(
        &H[(size_t)(b * LL + l0 + l) * DH + d0 + d]);
    tile[d + 0][l] = f2bf(v.x);
    tile[d + 1][l] = f2bf(v.y);
    tile[d + 2][l] = f2bf(v.z);
    tile[d + 3][l] = f2bf(v.w);
  }
  __syncthreads();
#pragma unroll
  for (int i = 0; i < 4; ++i) {
    int s = i * 256 + t;
    int d = s >> 4;          // 0..63
    int l = (s & 15) * 4;    // 0..60
    ushort4 o;
    o.x = tile[d][l + 0];
    o.y = tile[d][l + 1];
    o.z = tile[d][l + 2];
    o.w = tile[d][l + 3];
    *reinterpret_cast<ushort4*>(
        &Ht[(size_t)(b * DH + d0 + d) * LL + l0 + l]) = o;
  }
}

// ---------------------------------------------------------------- projection
// Out[m][n] = bf16( sum_k A[m][k] * W[n][k] ), A f32 MxKd, W f32 256xKd.
// 128x128 tile, BK=64, 4 waves (2x2), each wave 64x64 (4x4 16x16 frags).
__global__ __launch_bounds__(256) void k_proj(
    const float* __restrict__ A, const float* __restrict__ W,
    unsigned short* __restrict__ Out, int Kd) {
  __shared__ unsigned short Al[128][72];
  __shared__ unsigned short Bl[128][72];
  const int m0 = blockIdx.x * 128;
  const int n0 = blockIdx.y * 128;
  const int tid = threadIdx.x;
  const int lane = tid & 63;
  const int wave = tid >> 6;
  const int wm = (wave & 1) * 64;
  const int wn = (wave >> 1) * 64;
  const int fr = lane & 15;
  const int fg = lane >> 4;
  f32x4 acc[4][4] = {};
  for (int k0 = 0; k0 < Kd; k0 += 64) {
    __syncthreads();
#pragma unroll
    for (int i = 0; i < 8; ++i) {
      int s = i * 256 + tid;   // 0..2047
      int r = s >> 4;          // 0..127
      int c = (s & 15) * 4;    // 0..60
      float4 va = *reinterpret_cast<const float4*>(&A[(size_t)(m0 + r) * Kd + k0 + c]);
      ushort4 ua;
      ua.x = f2bf(va.x); ua.y = f2bf(va.y); ua.z = f2bf(va.z); ua.w = f2bf(va.w);
      *reinterpret_cast<ushort4*>(&Al[r][c]) = ua;
      float4 vb = *reinterpret_cast<const float4*>(&W[(size_t)(n0 + r) * Kd + k0 + c]);
      ushort4 ub;
      ub.x = f2bf(vb.x); ub.y = f2bf(vb.y); ub.z = f2bf(vb.z); ub.w = f2bf(vb.w);
      *reinterpret_cast<ushort4*>(&Bl[r][c]) = ub;
    }
    __syncthreads();
#pragma unroll
    for (int kk = 0; kk < 64; kk += 32) {
      s16x8 af[4], bfr[4];
#pragma unroll
      for (int mi = 0; mi < 4; ++mi)
        af[mi] = *reinterpret_cast<const s16x8*>(&Al[wm + mi * 16 + fr][kk + fg * 8]);
#pragma unroll
      for (int ni = 0; ni < 4; ++ni)
        bfr[ni] = *reinterpret_cast<const s16x8*>(&Bl[wn + ni * 16 + fr][kk + fg * 8]);
#pragma unroll
      for (int mi = 0; mi < 4; ++mi)
#pragma unroll
        for (int ni = 0; ni < 4; ++ni)
          acc[mi][ni] = __builtin_amdgcn_mfma_f32_16x16x32_bf16(af[mi], bfr[ni], acc[mi][ni], 0, 0, 0);
    }
  }
#pragma unroll
  for (int mi = 0; mi < 4; ++mi)
#pragma unroll
    for (int ni = 0; ni < 4; ++ni)
#pragma unroll
      for (int r = 0; r < 4; ++r) {
        int row = m0 + wm + mi * 16 + fg * 4 + r;
        int col = n0 + wn + ni * 16 + fr;
        Out[(size_t)row * PP + col] = f2bf(acc[mi][ni][r]);
      }
}

// ---------------------------------------------------------------- attention
// Per (b, 16 t-rows): S = Qb*Kb^T, e = exp(S*scale) (unnormalized, masked),
// store e as bf16, accumulate per-row sums -> Lsum. 4 waves, 512-wide L chunks.
__global__ __launch_bounds__(256) void k_attn(
    const unsigned short* __restrict__ Qb, const unsigned short* __restrict__ Kb,
    const unsigned char* __restrict__ mask,
    unsigned short* __restrict__ E, float* __restrict__ Lsum) {
  __shared__ float red[4][16];
  const int t0 = blockIdx.x * 16;
  const int b = blockIdx.y;
  const int tid = threadIdx.x;
  const int lane = tid & 63;
  const int wave = tid >> 6;
  const int fr = lane & 15;
  const int fg = lane >> 4;
  const float C = 0.09016844005556021f;  // (1/16) * log2(e)
  s16x8 qf[8];
  const unsigned short* qbase = Qb + (size_t)(b * TT + t0 + fr) * PP + fg * 8;
#pragma unroll
  for (int s = 0; s < 8; ++s)
    qf[s] = *reinterpret_cast<const s16x8*>(qbase + s * 32);
  float psum[4] = {0.f, 0.f, 0.f, 0.f};
  const int lbase = wave * 512;
  for (int fc = 0; fc < 32; ++fc) {
    const int col0 = lbase + fc * 16;
    const unsigned short* kbase = Kb + (size_t)(b * LL + col0 + fr) * PP + fg * 8;
    f32x4 acc = {0.f, 0.f, 0.f, 0.f};
#pragma unroll
    for (int s = 0; s < 8; ++s) {
      s16x8 kf = *reinterpret_cast<const s16x8*>(kbase + s * 32);
      acc = __builtin_amdgcn_mfma_f32_16x16x32_bf16(qf[s], kf, acc, 0, 0, 0);
    }
    const int col = col0 + fr;
    const bool msk = mask[b * LL + col] != 0;
#pragma unroll
    for (int r = 0; r < 4; ++r) {
      float e = msk ? 0.f : exp2f(fminf(acc[r] * C, 80.f));
      psum[r] += e;
      E[(size_t)(b * TT + t0 + fg * 4 + r) * LL + col] = f2bf(e);
    }
  }
#pragma unroll
  for (int r = 0; r < 4; ++r) {
#pragma unroll
    for (int off = 1; off < 16; off <<= 1)
      psum[r] += __shfl_xor(psum[r], off, 64);
  }
  if (fr == 0) {
#pragma unroll
    for (int r = 0; r < 4; ++r) red[wave][fg * 4 + r] = psum[r];
  }
  __syncthreads();
  if (tid < 16) {
    float s = red[0][tid] + red[1][tid] + red[2][tid] + red[3][tid];
    Lsum[b * TT + t0 + tid] = fmaxf(s, 1e-30f);
  }
}

// ---------------------------------------------------------------- PV
// Z[b][t][d] = (sum_l E[t][l] * H[l][d]) / Lsum[t].
// USE_HT: B-operand from Ht bf16 (row-contiguous). Fallback: stage f32 H transposed.
template <bool USE_HT>
__global__ __launch_bounds__(256) void k_pv(
    const unsigned short* __restrict__ E, const unsigned short* __restrict__ Ht,
    const float* __restrict__ Hf, const float* __restrict__ Lsum,
    float* __restrict__ Z) {
  __shared__ unsigned short Al[128][72];
  __shared__ unsigned short Bl[128][72];
  const int n0 = blockIdx.x * 128;  // d
  const int m0 = blockIdx.y * 128;  // t
  const int b = blockIdx.z;
  const int tid = threadIdx.x;
  const int lane = tid & 63;
  const int wave = tid >> 6;
  const int wm = (wave & 1) * 64;
  const int wn = (wave >> 1) * 64;
  const int fr = lane & 15;
  const int fg = lane >> 4;
  const unsigned short* Eb = E + (size_t)b * TT * LL;
  f32x4 acc[4][4] = {};
  for (int k0 = 0; k0 < LL; k0 += 64) {
    __syncthreads();
#pragma unroll
    for (int i = 0; i < 4; ++i) {
      int s = i * 256 + tid;  // 0..1023
      int r = s >> 3;         // 0..127
      int c = (s & 7) * 8;    // 0..56
      *reinterpret_cast<s16x8*>(&Al[r][c]) =
          *reinterpret_cast<const s16x8*>(&Eb[(size_t)(m0 + r) * LL + k0 + c]);
    }
    if (USE_HT) {
      const unsigned short* Hb = Ht + (size_t)b * DH * LL;
#pragma unroll
      for (int i = 0; i < 4; ++i) {
        int s = i * 256 + tid;
        int r = s >> 3;
        int c = (s & 7) * 8;
        *reinterpret_cast<s16x8*>(&Bl[r][c]) =
            *reinterpret_cast<const s16x8*>(&Hb[(size_t)(n0 + r) * LL + k0 + c]);
      }
    } else {
#pragma unroll
      for (int i = 0; i < 8; ++i) {
        int s = i * 256 + tid;   // 0..2047
        int l = s >> 5;          // 0..63
        int d = (s & 31) * 4;    // 0..124
        float4 v = *reinterpret_cast<const float4*>(
            &Hf[(size_t)(b * LL + k0 + l) * DH + n0 + d]);
        Bl[d + 0][l] = f2bf(v.x);
        Bl[d + 1][l] = f2bf(v.y);
        Bl[d + 2][l] = f2bf(v.z);
        Bl[d + 3][l] = f2bf(v.w);
      }
    }
    __syncthreads();
#pragma unroll
    for (int kk = 0; kk < 64; kk += 32) {
      s16x8 af[4], bfr[4];
#pragma unroll
      for (int mi = 0; mi < 4; ++mi)
        af[mi] = *reinterpret_cast<const s16x8*>(&Al[wm + mi * 16 + fr][kk + fg * 8]);
#pragma unroll
      for (int ni = 0; ni < 4; ++ni)
        bfr[ni] = *reinterpret_cast<const s16x8*>(&Bl[wn + ni * 16 + fr][kk + fg * 8]);
#pragma unroll
      for (int mi = 0; mi < 4; ++mi)
#pragma unroll
        for (int ni = 0; ni < 4; ++ni)
          acc[mi][ni] = __builtin_amdgcn_mfma_f32_16x16x32_bf16(af[mi], bfr[ni], acc[mi][ni], 0, 0, 0);
    }
  }
#pragma unroll
  for (int mi = 0; mi < 4; ++mi)
#pragma unroll
    for (int r = 0; r < 4; ++r) {
      int row = m0 + wm + mi * 16 + fg * 4 + r;
      float inv = 1.0f / Lsum[b * TT + row];
#pragma unroll
      for (int ni = 0; ni < 4; ++ni) {
        int col = n0 + wn + ni * 16 + fr;
        Z[(size_t)(b * TT + row) * DH + col] = acc[mi][ni][r] * inv;
      }
    }
}

// ---------------------------------------------------------------- launch
extern "C" void kernel_launch(void* const* d_in, const int* in_sizes, int n_in,
                              void* d_out, int out_size, void* d_ws, size_t ws_size,
                              hipStream_t stream) {
  const float* H = (const float*)d_in[0];
  const float* G = (const float*)d_in[1];
  const unsigned char* mask = (const unsigned char*)d_in[2];
  const float* Wk = (const float*)d_in[3];
  const float* Wq = (const float*)d_in[4];
  float* Z = (float*)d_out;
  char* ws = (char*)d_ws;

  // ws layout (bytes); Ht last so the small layout is a prefix of the full one.
  const size_t OFF_KB = 0;                                   // 16 MiB (B*L*P bf16)
  const size_t OFF_QB = OFF_KB + (size_t)BB * LL * PP * 2;   // + 4 MiB (B*T*P bf16)
  const size_t OFF_E  = OFF_QB + (size_t)BB * TT * PP * 2;   // +32 MiB (B*T*L bf16)
  const size_t OFF_LS = OFF_E + (size_t)BB * TT * LL * 2;    // +32 KiB (B*T f32)
  const size_t OFF_HT = OFF_LS + (size_t)BB * TT * 4;
  const size_t WS_FULL = OFF_HT + (size_t)BB * DH * LL * 2;  // +64 MiB (B*Dh*L bf16)

  unsigned short* Kb = (unsigned short*)(ws + OFF_KB);
  unsigned short* Qb = (unsigned short*)(ws + OFF_QB);
  unsigned short* E = (unsigned short*)(ws + OFF_E);
  float* Lsum = (float*)(ws + OFF_LS);
  unsigned short* Ht = (unsigned short*)(ws + OFF_HT);

  const bool useHt = ws_size >= WS_FULL;

  if (useHt)
    k_transpose_h<<<dim3(LL / 64, DH / 64, BB), 256, 0, stream>>>(H, Ht);
  k_proj<<<dim3(BB * LL / 128, 2), 256, 0, stream>>>(H, Wk, Kb, DH);
  k_proj<<<dim3(BB * TT / 128, 2), 256, 0, stream>>>(G, Wq, Qb, DG);
  k_attn<<<dim3(TT / 16, BB), 256, 0, stream>>>(Qb, Kb, mask, E, Lsum);
  if (useHt)
    k_pv<true><<<dim3(DH / 128, TT / 128, BB), 256, 0, stream>>>(E, Ht, H, Lsum, Z);
  else
    k_pv<false><<<dim3(DH / 128, TT / 128, BB), 256, 0, stream>>>(E, Ht, H, Lsum, Z);
}